// Round 7
// baseline (647.812 us; speedup 1.0000x reference)
//
#include <hip/hip_runtime.h>
#include <cstdint>

#define BATCH 128
#define NODES 1023
#define LEAVES 512
#define IN_DIM 300
#define MEM 300
#define NP 320              // padded per-set N (and per-child K)
#define OUT_HALF (BATCH*MEM)

typedef __bf16   bf16x8 __attribute__((ext_vector_type(8)));
typedef short    s16x8  __attribute__((ext_vector_type(8)));
typedef short    s16x4  __attribute__((ext_vector_type(4)));
typedef float    f32x4  __attribute__((ext_vector_type(4)));
typedef _Float16 half_t;

__device__ __forceinline__ short f2bf(float f) {
    unsigned u = __float_as_uint(f);
    u += 0x7fff + ((u >> 16) & 1);
    return (short)(u >> 16);
}
__device__ __forceinline__ float sigf(float x)  { return 1.0f / (1.0f + __expf(-x)); }
__device__ __forceinline__ float tanhf_(float x){ return 1.0f - 2.0f / (1.0f + __expf(2.0f * x)); }

__device__ __forceinline__ f32x4 mfma16(s16x8 a, s16x8 b, f32x4 c) {
    return __builtin_amdgcn_mfma_f32_16x16x32_bf16(
        __builtin_bit_cast(bf16x8, a), __builtin_bit_cast(bf16x8, b), c, 0, 0, 0);
}

// async 16B/lane global->LDS: lds dst = wave-uniform base + lane*16
__device__ __forceinline__ void dma16(const short* src, short* ldsBase) {
    __builtin_amdgcn_global_load_lds(
        (const __attribute__((address_space(1))) unsigned int*)src,
        (__attribute__((address_space(3))) unsigned int*)ldsBase,
        16, 0, 0);
}

// f32x8 -> bf16x8 (all 8 valid)
__device__ __forceinline__ s16x8 cvt8f(f32x4 lo, f32x4 hi) {
    s16x8 r;
#pragma unroll
    for (int j = 0; j < 4; ++j) { r[j] = f2bf(lo[j]); r[4 + j] = f2bf(hi[j]); }
    return r;
}
// masked variant for the last K-step (k >= IN_DIM -> 0)
__device__ __forceinline__ s16x8 cvt8m(f32x4 lo, f32x4 hi, int koff) {
    s16x8 r;
#pragma unroll
    for (int j = 0; j < 4; ++j) {
        r[j]     = (koff + j     < IN_DIM) ? f2bf(lo[j]) : (short)0;
        r[4 + j] = (koff + 4 + j < IN_DIM) ? f2bf(hi[j]) : (short)0;
    }
    return r;
}

// ---------- weight packing: B-fragment order ----------
// frag-block (kb,s,nb): 64 lanes x 8 bf16; lane l holds B[k=kb*32+(l>>4)*8+j][n=nb*16+(l&15)]
__global__ __launch_bounds__(256) void pack_node_w(
    const float* __restrict__ Wiouh, const float* __restrict__ Wfh, short* __restrict__ Wpk)
{
    int gid = blockIdx.x * 256 + threadIdx.x;           // 2000 frags * 64 lanes
    if (gid >= 2000 * 64) return;
    int fb = gid >> 6, l = gid & 63;
    int kb = fb / 100, rem = fb % 100, s = rem / 20, nb = rem % 20;
    int n = nb * 16 + (l & 15);
    int kbase = kb * 32 + (l >> 4) * 8;                 // k' in [0,640)
    short v[8];
#pragma unroll
    for (int j = 0; j < 8; ++j) {
        int kp = kbase + j;
        int side = kp >= NP;
        int kk = kp - side * NP;
        float f = 0.0f;
        if (kk < MEM && n < MEM) {
            int k = side * MEM + kk;
            f = (s < 3) ? Wiouh[(size_t)k * 900 + s * 300 + n]
                        : Wfh[(size_t)k * 600 + (s - 3) * 300 + n];
        }
        v[j] = f2bf(f);
    }
    *(s16x8*)&Wpk[(size_t)gid * 8] = *(s16x8*)v;
}

__global__ __launch_bounds__(256) void pack_leaf_w(
    const float* __restrict__ Wfioux, short* __restrict__ Wpk)
{
    int gid = blockIdx.x * 256 + threadIdx.x;           // 600 frags * 64 lanes
    if (gid >= 600 * 64) return;
    int fb = gid >> 6, l = gid & 63;
    int kb = fb / 60, rem = fb % 60, s = rem / 20, nb = rem % 20;
    int n = nb * 16 + (l & 15);
    int kbase = kb * 32 + (l >> 4) * 8;                 // k' in [0,320)
    short v[8];
#pragma unroll
    for (int j = 0; j < 8; ++j) {
        int kp = kbase + j;
        float f = 0.0f;
        if (kp < IN_DIM && n < MEM)
            f = Wfioux[(size_t)kp * 1200 + (s + 1) * 300 + n];
        v[j] = f2bf(f);
    }
    *(s16x8*)&Wpk[(size_t)gid * 8] = *(s16x8*)v;
}

// ---------- leaf GEMM+gates: block = 1 leaf x 32-col group ----------
// Reads inputs f32 DIRECTLY (pack_x removed): raw-f32 A-register ring (4-deep),
// f2bf conversion happens in the step body AFTER the counted wait, so dma/load
// latency stays hidden. Last K-step (kb=9, k 288..319) masks k>=300 to 0 at
// convert time (loads stay unconditional for stable vmcnt counts; OOB lanes
// read in-tensor bytes of the next row, masked away; global max index is
// in-bounds). 2 dma + 4 f32x4 A-loads = 6 vmem ops/wave/step -> steady
// vmcnt(12). XCD swizzle: a leaf's 10 col-groups on one XCD (A panel: 1x HBM
// + 9x L2).
__global__ __launch_bounds__(256, 3) void leaf_mfma(
    const float* __restrict__ inputs, const short* __restrict__ Wpk,
    const float* __restrict__ b_fioux, half_t* __restrict__ C, short* __restrict__ H)
{
    __shared__ short Bs[4][8 * 512];                    // 4 ring bufs x 8 frag slots
    const int t = threadIdx.x;
    const int l = t & 63, w = t >> 6;                   // 4 waves, w = row-group
    const int lane16 = l & 15, quad = l >> 4;

    // bid = (leaf%8) + 8*(y + 10*(leaf/8))
    const int bid = blockIdx.x;
    const int xcd = bid & 7, tt = bid >> 3;
    const int y = tt % 10;                              // 32-col group 0..9
    const int leaf = (tt / 10) * 8 + xcd;

    f32x4 acc[3][2][2];                                 // [set][col-frag][row-half]
#pragma unroll
    for (int s = 0; s < 3; ++s)
#pragma unroll
        for (int f = 0; f < 2; ++f)
#pragma unroll
            for (int mi = 0; mi < 2; ++mi) acc[s][f][mi] = (f32x4)(0.0f);

    f32x4 Af[4][2][2];                                  // ring slot x row-half x lo/hi

// 6 real frags (3 sets x 2) padded to 8 (slots 6,7 dup 0,1): 2 dma/wave/step
#define L_STAGE(KB, BUF) do {                                                    \
    _Pragma("unroll")                                                            \
    for (int fl = w * 2; fl < w * 2 + 2; ++fl) {                                 \
        int rfl_ = (fl < 6) ? fl : fl - 6;                                       \
        int s_ = rfl_ >> 1, f_ = rfl_ & 1;                                       \
        const short* src_ = Wpk +                                                \
            ((size_t)(((KB) * 3 + s_) * 20 + y * 2 + f_) * 64 + l) * 8;          \
        dma16(src_, &Bs[BUF][fl * 512]);                                         \
    } } while (0)

#define L_ALOAD(KB, SLOT) do {                                                   \
    const int koff_ = (KB) * 32 + quad * 8;                                      \
    const float* p0_ = inputs +                                                  \
        ((size_t)(w * 32 + lane16) * NODES + leaf) * IN_DIM + koff_;             \
    const float* p1_ = inputs +                                                  \
        ((size_t)(w * 32 + 16 + lane16) * NODES + leaf) * IN_DIM + koff_;        \
    Af[SLOT][0][0] = *(const f32x4*)(p0_);                                       \
    Af[SLOT][0][1] = *(const f32x4*)(p0_ + 4);                                   \
    Af[SLOT][1][0] = *(const f32x4*)(p1_);                                       \
    Af[SLOT][1][1] = *(const f32x4*)(p1_ + 4);                                   \
} while (0)

    // prologue: issue steps 0,1,2 (18 vmem ops per wave in flight)
    L_STAGE(0, 0); L_ALOAD(0, 0);
    L_STAGE(1, 1); L_ALOAD(1, 1);
    L_STAGE(2, 2); L_ALOAD(2, 2);

// steady: before step ST, issued = 18+6*ST, need A(ST) end = 18+6*(ST-2)
// -> vmcnt(12). Ring distance 3 on both B and A keeps 2 full steps in flight.
#define L_STEP(ST, WAITN) do {                                                   \
    asm volatile("s_waitcnt vmcnt(" #WAITN ")" ::: "memory");                    \
    __builtin_amdgcn_s_barrier();                                                \
    asm volatile("" ::: "memory");                                               \
    if ((ST) + 3 < 10) { L_STAGE((ST) + 3, ((ST) + 3) & 3);                      \
                         L_ALOAD((ST) + 3, ((ST) + 3) & 3); }                    \
    s16x8 a0_, a1_;                                                              \
    if ((ST) < 9) {                                                              \
        a0_ = cvt8f(Af[(ST) & 3][0][0], Af[(ST) & 3][0][1]);                     \
        a1_ = cvt8f(Af[(ST) & 3][1][0], Af[(ST) & 3][1][1]);                     \
    } else {                                                                     \
        const int ko_ = (ST) * 32 + quad * 8;                                    \
        a0_ = cvt8m(Af[(ST) & 3][0][0], Af[(ST) & 3][0][1], ko_);                \
        a1_ = cvt8m(Af[(ST) & 3][1][0], Af[(ST) & 3][1][1], ko_);                \
    }                                                                            \
    _Pragma("unroll")                                                            \
    for (int s_ = 0; s_ < 3; ++s_) {                                             \
        _Pragma("unroll")                                                        \
        for (int f_ = 0; f_ < 2; ++f_) {                                         \
            s16x8 b_ = *(const s16x8*)&Bs[(ST) & 3][(s_ * 2 + f_) * 512 + l * 8];\
            acc[s_][f_][0] = mfma16(a0_, b_, acc[s_][f_][0]);                    \
            acc[s_][f_][1] = mfma16(a1_, b_, acc[s_][f_][1]);                    \
        }                                                                        \
    } } while (0)

    L_STEP(0, 12); L_STEP(1, 12); L_STEP(2, 12); L_STEP(3, 12); L_STEP(4, 12);
    L_STEP(5, 12); L_STEP(6, 12); L_STEP(7, 12); L_STEP(8, 6);  L_STEP(9, 0);

#undef L_STEP
#undef L_ALOAD
#undef L_STAGE

#pragma unroll
    for (int f = 0; f < 2; ++f) {
        const int col = y * 32 + f * 16 + lane16;
        const bool valid = col < MEM;
        float bi = 0, bo = 0, bu = 0;
        if (valid) { bi = b_fioux[300 + col]; bo = b_fioux[600 + col]; bu = b_fioux[900 + col]; }
#pragma unroll
        for (int mi = 0; mi < 2; ++mi)
#pragma unroll
            for (int r = 0; r < 4; ++r) {
                int b = w * 32 + mi * 16 + quad * 4 + r;
                size_t hIdx = ((size_t)leaf * BATCH + b) * NP + col;
                if (valid) {
                    float ig = sigf(acc[0][f][mi][r] + bi);
                    float og = sigf(acc[1][f][mi][r] + bo);
                    float ug = tanhf_(acc[2][f][mi][r] + bu);
                    float c = ig * ug;
                    float h = og * tanhf_(c);
                    C[((size_t)leaf * BATCH + b) * MEM + col] = (half_t)c;
                    H[hIdx] = f2bf(h);
                } else {
                    H[hIdx] = 0;
                }
            }
    }
}

// ---------- internal node GEMM+gates: round-3 config verbatim ----------
// K32, 20 steps, 12-frag staging (slots 10,11 dup), 4-buf ring depth-3,
// steady vmcnt(10), 3 blocks/CU. XCD swizzle groups a node's 10 col-groups
// on one XCD (child H/C: 1x HBM/L3 + 9x L2). Used for ALL internal levels
// (per-level launches; no inter-block sync anywhere -> cannot hang).
__global__ __launch_bounds__(256, 3) void node_mfma(
    const short* __restrict__ Wpk, const float* __restrict__ b_fioux,
    const int* __restrict__ left_idx, const int* __restrict__ right_idx,
    half_t* __restrict__ C, short* __restrict__ H,
    int level_start, int level_size, float* __restrict__ out)
{
    __shared__ short Bs[4][12 * 512];                   // 4 ring bufs x 12KB
    const int t = threadIdx.x;
    const int l = t & 63, w = t >> 6;                   // 4 waves, w = row-group
    const int lane16 = l & 15, quad = l >> 4;

    const int bid = blockIdx.x;
    int nidx, y;
    if ((level_size & 7) == 0) {
        const int xcd = bid & 7, tt = bid >> 3;
        y = tt % 10;
        nidx = (tt / 10) * 8 + xcd;
    } else {
        nidx = bid % level_size;
        y = bid / level_size;
    }
    const int node = level_start + nidx;

    const int li = left_idx[node], ri = right_idx[node];
    const short* HL = H + (size_t)li * BATCH * NP;
    const short* HR = H + (size_t)ri * BATCH * NP;

    f32x4 acc[5][2][2];                                 // [set][frag][row-half]
#pragma unroll
    for (int s = 0; s < 5; ++s)
#pragma unroll
        for (int f = 0; f < 2; ++f)
#pragma unroll
            for (int mi = 0; mi < 2; ++mi) acc[s][f][mi] = (f32x4)(0.0f);

    s16x8 A[4][2];

#define N_STAGE(KB, BUF) do {                                                    \
    _Pragma("unroll")                                                            \
    for (int fl = w; fl < 12; fl += 4) {                                         \
        int rfl_ = (fl < 10) ? fl : fl - 10;            /* slots 10,11: dup */   \
        int s_ = rfl_ >> 1, f_ = rfl_ & 1;                                       \
        const short* src_ = Wpk +                                                \
            ((size_t)(((KB) * 5 + s_) * 20 + y * 2 + f_) * 64 + l) * 8;          \
        dma16(src_, &Bs[BUF][fl * 512]);                                         \
    } } while (0)

#define N_ALOAD(KB, SLOT) do {                                                   \
    const short* Hb_ = (((KB) >= 10) ? HR : HL) +                                \
                       ((KB) - (((KB) >= 10) ? 10 : 0)) * 32 + quad * 8;         \
    A[SLOT][0] = *(const s16x8*)(Hb_ + (size_t)(w * 32 + lane16) * NP);          \
    A[SLOT][1] = *(const s16x8*)(Hb_ + (size_t)(w * 32 + 16 + lane16) * NP);     \
} while (0)

    N_STAGE(0, 0); N_ALOAD(0, 0);
    N_STAGE(1, 1); N_ALOAD(1, 1);
    N_STAGE(2, 2); N_ALOAD(2, 2);

#define N_STEP(ST, WAITN) do {                                                   \
    asm volatile("s_waitcnt vmcnt(" #WAITN ")" ::: "memory");                    \
    __builtin_amdgcn_s_barrier();                                                \
    asm volatile("" ::: "memory");                                               \
    if ((ST) + 3 < 20) { N_STAGE((ST) + 3, ((ST) + 3) & 3);                      \
                         N_ALOAD((ST) + 3, ((ST) + 3) & 3); }                    \
    _Pragma("unroll")                                                            \
    for (int s_ = 0; s_ < 5; ++s_) {                                             \
        _Pragma("unroll")                                                        \
        for (int f_ = 0; f_ < 2; ++f_) {                                         \
            s16x8 b_ = *(const s16x8*)&Bs[(ST) & 3][(s_ * 2 + f_) * 512 + l * 8];\
            acc[s_][f_][0] = mfma16(A[(ST) & 3][0], b_, acc[s_][f_][0]);         \
            acc[s_][f_][1] = mfma16(A[(ST) & 3][1], b_, acc[s_][f_][1]);         \
        }                                                                        \
    } } while (0)

    N_STEP(0, 10);  N_STEP(1, 10);  N_STEP(2, 10);  N_STEP(3, 10);  N_STEP(4, 10);
    N_STEP(5, 10);  N_STEP(6, 10);  N_STEP(7, 10);  N_STEP(8, 10);  N_STEP(9, 10);
    N_STEP(10, 10); N_STEP(11, 10); N_STEP(12, 10); N_STEP(13, 10); N_STEP(14, 10);
    N_STEP(15, 10); N_STEP(16, 10); N_STEP(17, 10); N_STEP(18, 5);  N_STEP(19, 0);

#undef N_STEP
#undef N_ALOAD
#undef N_STAGE

#pragma unroll
    for (int f = 0; f < 2; ++f) {
        const int col = y * 32 + f * 16 + lane16;
        const bool valid = col < MEM;
        float bff = 0, bi = 0, bo = 0, bu = 0;
        if (valid) {
            bff = b_fioux[col]; bi = b_fioux[300 + col];
            bo = b_fioux[600 + col]; bu = b_fioux[900 + col];
        }
#pragma unroll
        for (int mi = 0; mi < 2; ++mi)
#pragma unroll
            for (int r = 0; r < 4; ++r) {
                int row = w * 32 + mi * 16 + quad * 4 + r;
                size_t hIdx = ((size_t)node * BATCH + row) * NP + col;
                if (valid) {
                    float cl = (float)C[((size_t)li * BATCH + row) * MEM + col];
                    float cr = (float)C[((size_t)ri * BATCH + row) * MEM + col];
                    float ig = sigf(acc[0][f][mi][r] + bi);
                    float og = sigf(acc[1][f][mi][r] + bo);
                    float ug = tanhf_(acc[2][f][mi][r] + bu);
                    float fl = sigf(acc[3][f][mi][r] + bff);
                    float fr = sigf(acc[4][f][mi][r] + bff);
                    float c = ig * ug + fl * cl + fr * cr;
                    float h = og * tanhf_(c);
                    C[((size_t)node * BATCH + row) * MEM + col] = (half_t)c;
                    H[hIdx] = f2bf(h);
                    if (out) {
                        out[row * MEM + col] = c;
                        out[OUT_HALF + row * MEM + col] = h;
                    }
                } else {
                    H[hIdx] = 0;
                }
            }
    }
}

extern "C" void kernel_launch(void* const* d_in, const int* in_sizes, int n_in,
                              void* d_out, int out_size, void* d_ws, size_t ws_size,
                              hipStream_t stream) {
    const float* inputs  = (const float*)d_in[0];
    const float* Wfioux  = (const float*)d_in[1];
    const float* b_fioux = (const float*)d_in[2];
    const float* Wiouh   = (const float*)d_in[3];
    const float* Wfh     = (const float*)d_in[4];
    const int*   left_idx  = (const int*)d_in[5];
    const int*   right_idx = (const int*)d_in[6];

    half_t* C   = (half_t*)d_ws;                              // [1023][128][300] fp16
    short*  H   = (short*)(C + (size_t)NODES * BATCH * MEM);  // [1023][128][320] bf16
    short* WpkN = H + (size_t)NODES * BATCH * NP;             // 2000 frag-blocks
    short* WpkL = WpkN + (size_t)2000 * 512;                  // 600 frag-blocks
    float* out  = (float*)d_out;

    pack_leaf_w<<<150, 256, 0, stream>>>(Wfioux, WpkL);
    pack_node_w<<<500, 256, 0, stream>>>(Wiouh, Wfh, WpkN);

    leaf_mfma<<<LEAVES * 10, 256, 0, stream>>>(inputs, WpkL, b_fioux, C, H);

    static const int starts[9] = {512, 768, 896, 960, 992, 1008, 1016, 1020, 1022};
    static const int sizes [9] = {256, 128,  64,  32,  16,    8,    4,    2,    1};
    for (int lvl = 0; lvl < 9; ++lvl) {
        bool root = (lvl == 8);
        node_mfma<<<sizes[lvl] * 10, 256, 0, stream>>>(
            WpkN, b_fioux, left_idx, right_idx, C, H, starts[lvl], sizes[lvl],
            root ? out : nullptr);
    }
}

// Round 8
// 632.046 us; speedup vs baseline: 1.0249x; 1.0249x over previous
//
#include <hip/hip_runtime.h>
#include <cstdint>

#define BATCH 128
#define NODES 1023
#define LEAVES 512
#define IN_DIM 300
#define MEM 300
#define NP 320              // padded per-set N (and per-child K)
#define KB_CNT 40           // NP/8 fragment-chunks per row
#define HNODE (KB_CNT*BATCH*8)   // shorts per node in fragment-ready H (=40960)
#define OUT_HALF (BATCH*MEM)

typedef __bf16   bf16x8 __attribute__((ext_vector_type(8)));
typedef short    s16x8  __attribute__((ext_vector_type(8)));
typedef float    f32x4  __attribute__((ext_vector_type(4)));
typedef _Float16 half_t;

__device__ __forceinline__ short f2bf(float f) {
    unsigned u = __float_as_uint(f);
    u += 0x7fff + ((u >> 16) & 1);
    return (short)(u >> 16);
}
__device__ __forceinline__ float sigf(float x)  { return 1.0f / (1.0f + __expf(-x)); }
__device__ __forceinline__ float tanhf_(float x){ return 1.0f - 2.0f / (1.0f + __expf(2.0f * x)); }

__device__ __forceinline__ f32x4 mfma16(s16x8 a, s16x8 b, f32x4 c) {
    return __builtin_amdgcn_mfma_f32_16x16x32_bf16(
        __builtin_bit_cast(bf16x8, a), __builtin_bit_cast(bf16x8, b), c, 0, 0, 0);
}

// async 16B/lane global->LDS: lds dst = wave-uniform base + lane*16
__device__ __forceinline__ void dma16(const short* src, short* ldsBase) {
    __builtin_amdgcn_global_load_lds(
        (const __attribute__((address_space(1))) unsigned int*)src,
        (__attribute__((address_space(3))) unsigned int*)ldsBase,
        16, 0, 0);
}

// ---------- weight packing: B-fragment order ----------
// frag-block (kb,s,nb): 64 lanes x 8 bf16; lane l holds B[k=kb*32+(l>>4)*8+j][n=nb*16+(l&15)]
__global__ __launch_bounds__(256) void pack_node_w(
    const float* __restrict__ Wiouh, const float* __restrict__ Wfh, short* __restrict__ Wpk)
{
    int gid = blockIdx.x * 256 + threadIdx.x;           // 2000 frags * 64 lanes
    if (gid >= 2000 * 64) return;
    int fb = gid >> 6, l = gid & 63;
    int kb = fb / 100, rem = fb % 100, s = rem / 20, nb = rem % 20;
    int n = nb * 16 + (l & 15);
    int kbase = kb * 32 + (l >> 4) * 8;                 // k' in [0,640)
    short v[8];
#pragma unroll
    for (int j = 0; j < 8; ++j) {
        int kp = kbase + j;
        int side = kp >= NP;
        int kk = kp - side * NP;
        float f = 0.0f;
        if (kk < MEM && n < MEM) {
            int k = side * MEM + kk;
            f = (s < 3) ? Wiouh[(size_t)k * 900 + s * 300 + n]
                        : Wfh[(size_t)k * 600 + (s - 3) * 300 + n];
        }
        v[j] = f2bf(f);
    }
    *(s16x8*)&Wpk[(size_t)gid * 8] = *(s16x8*)v;
}

__global__ __launch_bounds__(256) void pack_leaf_w(
    const float* __restrict__ Wfioux, short* __restrict__ Wpk)
{
    int gid = blockIdx.x * 256 + threadIdx.x;           // 600 frags * 64 lanes
    if (gid >= 600 * 64) return;
    int fb = gid >> 6, l = gid & 63;
    int kb = fb / 60, rem = fb % 60, s = rem / 20, nb = rem % 20;
    int n = nb * 16 + (l & 15);
    int kbase = kb * 32 + (l >> 4) * 8;                 // k' in [0,320)
    short v[8];
#pragma unroll
    for (int j = 0; j < 8; ++j) {
        int kp = kbase + j;
        float f = 0.0f;
        if (kp < IN_DIM && n < MEM)
            f = Wfioux[(size_t)kp * 1200 + (s + 1) * 300 + n];
        v[j] = f2bf(f);
    }
    *(s16x8*)&Wpk[(size_t)gid * 8] = *(s16x8*)v;
}

// ---------- leaf-input packing: fragment-ready X2[leaf][kb][b][8] bf16 ----------
// Thread = one 16B output chunk (leaf, b, kb), kb fastest -> input reads are
// contiguous within a (b,leaf) row (coalesced); output writes 16B at 2KB
// stride (scattered; one-time cost). k >= 300 zero-filled.
__global__ __launch_bounds__(256) void pack_x2(
    const float* __restrict__ inputs, short* __restrict__ X)
{
    int gid = blockIdx.x * 256 + threadIdx.x;           // 512*128*40 chunks
    if (gid >= LEAVES * BATCH * KB_CNT) return;
    int kb = gid % KB_CNT;
    int rb = gid / KB_CNT;
    int b = rb % BATCH, leaf = rb / BATCH;
    const float* src = inputs + ((size_t)b * NODES + leaf) * IN_DIM + kb * 8;
    short v[8];
#pragma unroll
    for (int j = 0; j < 8; ++j) {
        int k = kb * 8 + j;
        v[j] = (k < IN_DIM) ? f2bf(src[j]) : (short)0;
    }
    *(s16x8*)&X[(size_t)((leaf * KB_CNT + kb) * BATCH + b) * 8] = *(s16x8*)v;
}

// ---------- leaf GEMM+gates: block = 1 leaf x 64-col group ----------
// Round-3 pipeline verbatim (4-buf ring depth-3, steady vmcnt(10), XCD
// swizzle), A-loads from fragment-ready X2: lane16 -> 16B stride -> 256B
// contiguous per quad-group (16 lines/instr vs 64 with row-major).
__global__ __launch_bounds__(256, 3) void leaf_mfma(
    const short* __restrict__ X, const short* __restrict__ Wpk,
    const float* __restrict__ b_fioux, half_t* __restrict__ C, short* __restrict__ H)
{
    __shared__ short Bs[4][12 * 512];                   // 4 ring bufs x 12 frags x 1KB
    const int t = threadIdx.x;
    const int l = t & 63, w = t >> 6;                   // 4 waves, w = row-group
    const int lane16 = l & 15, quad = l >> 4;

    // bid = (leaf%8) + 8*(y + 5*(leaf/8))  ->  decode:
    const int bid = blockIdx.x;
    const int xcd = bid & 7, tt = bid >> 3;
    const int y = tt % 5;                               // 64-col group 0..4
    const int leaf = (tt / 5) * 8 + xcd;

    const short* Xb = X + (size_t)leaf * HNODE;

    f32x4 acc[3][4][2];                                 // [set][frag][row-half]
#pragma unroll
    for (int s = 0; s < 3; ++s)
#pragma unroll
        for (int f = 0; f < 4; ++f)
#pragma unroll
            for (int mi = 0; mi < 2; ++mi) acc[s][f][mi] = (f32x4)(0.0f);

    s16x8 A[4][2];                                      // A-fragment ring (static idx only)

#define L_STAGE(KB, BUF) do {                                                    \
    _Pragma("unroll")                                                            \
    for (int fl = w; fl < 12; fl += 4) {                                         \
        int s_ = fl >> 2, f_ = fl & 3;                                           \
        const short* src_ = Wpk +                                                \
            ((size_t)(((KB) * 3 + s_) * 20 + y * 4 + f_) * 64 + l) * 8;          \
        dma16(src_, &Bs[BUF][fl * 512]);                                         \
    } } while (0)

#define L_ALOAD(KB, SLOT) do {                                                   \
    const short* p_ = Xb + (size_t)(((KB) * 4 + quad) * BATCH + w * 32 + lane16) * 8; \
    A[SLOT][0] = *(const s16x8*)(p_);                                            \
    A[SLOT][1] = *(const s16x8*)(p_ + 16 * 8);                                   \
} while (0)

    // prologue: issue steps 0,1,2 (15 vmem ops per wave in flight)
    L_STAGE(0, 0); L_ALOAD(0, 0);
    L_STAGE(1, 1); L_ALOAD(1, 1);
    L_STAGE(2, 2); L_ALOAD(2, 2);

// waitcnt BEFORE barrier: guarantees every wave's step-ST stage is complete when
// any wave crosses. issue AFTER barrier: ring distance 3 makes the WAR on buffer
// (ST+3)&3 == (ST-1)&3 safe (its readers finished before this barrier).
#define L_STEP(ST, WAITN) do {                                                   \
    asm volatile("s_waitcnt vmcnt(" #WAITN ")" ::: "memory");                    \
    __builtin_amdgcn_s_barrier();                                                \
    asm volatile("" ::: "memory");                                               \
    if ((ST) + 3 < 10) { L_STAGE((ST) + 3, ((ST) + 3) & 3);                      \
                         L_ALOAD((ST) + 3, ((ST) + 3) & 3); }                    \
    _Pragma("unroll")                                                            \
    for (int s_ = 0; s_ < 3; ++s_) {                                             \
        _Pragma("unroll")                                                        \
        for (int f_ = 0; f_ < 4; ++f_) {                                         \
            s16x8 b_ = *(const s16x8*)&Bs[(ST) & 3][(s_ * 4 + f_) * 512 + l * 8];\
            acc[s_][f_][0] = mfma16(A[(ST) & 3][0], b_, acc[s_][f_][0]);         \
            acc[s_][f_][1] = mfma16(A[(ST) & 3][1], b_, acc[s_][f_][1]);         \
        }                                                                        \
    } } while (0)

    L_STEP(0, 10); L_STEP(1, 10); L_STEP(2, 10); L_STEP(3, 10); L_STEP(4, 10);
    L_STEP(5, 10); L_STEP(6, 10); L_STEP(7, 10); L_STEP(8, 5);  L_STEP(9, 0);

#undef L_STEP
#undef L_ALOAD
#undef L_STAGE

#pragma unroll
    for (int f = 0; f < 4; ++f) {
        const int col = y * 64 + f * 16 + lane16;
        const bool valid = col < MEM;
        float bi = 0, bo = 0, bu = 0;
        if (valid) { bi = b_fioux[300 + col]; bo = b_fioux[600 + col]; bu = b_fioux[900 + col]; }
#pragma unroll
        for (int mi = 0; mi < 2; ++mi)
#pragma unroll
            for (int r = 0; r < 4; ++r) {
                int b = w * 32 + mi * 16 + quad * 4 + r;
                size_t hIdx = (size_t)leaf * HNODE +
                              (size_t)((col >> 3) * BATCH + b) * 8 + (col & 7);
                if (valid) {
                    float ig = sigf(acc[0][f][mi][r] + bi);
                    float og = sigf(acc[1][f][mi][r] + bo);
                    float ug = tanhf_(acc[2][f][mi][r] + bu);
                    float c = ig * ug;
                    float h = og * tanhf_(c);
                    C[((size_t)leaf * BATCH + b) * MEM + col] = (half_t)c;
                    H[hIdx] = f2bf(h);
                } else {
                    H[hIdx] = 0;
                }
            }
    }
}

// ---------- internal node GEMM+gates: round-3 pipeline, fragment-ready H ----------
// K32, 20 steps, 12-frag staging (slots 10,11 dup), 4-buf ring depth-3,
// steady vmcnt(10), 3 blocks/CU, XCD swizzle. A-loads from H[node][kb][b][8]:
// 16 lines/instr instead of 64 -> 4x fewer L2 requests (the round-3..5 wall).
__global__ __launch_bounds__(256, 3) void node_mfma(
    const short* __restrict__ Wpk, const float* __restrict__ b_fioux,
    const int* __restrict__ left_idx, const int* __restrict__ right_idx,
    half_t* __restrict__ C, short* __restrict__ H,
    int level_start, int level_size, float* __restrict__ out)
{
    __shared__ short Bs[4][12 * 512];                   // 4 ring bufs x 12KB
    const int t = threadIdx.x;
    const int l = t & 63, w = t >> 6;                   // 4 waves, w = row-group
    const int lane16 = l & 15, quad = l >> 4;

    const int bid = blockIdx.x;
    int nidx, y;
    if ((level_size & 7) == 0) {
        const int xcd = bid & 7, tt = bid >> 3;
        y = tt % 10;
        nidx = (tt / 10) * 8 + xcd;
    } else {
        nidx = bid % level_size;
        y = bid / level_size;
    }
    const int node = level_start + nidx;

    const int li = left_idx[node], ri = right_idx[node];
    const short* HL = H + (size_t)li * HNODE;
    const short* HR = H + (size_t)ri * HNODE;

    f32x4 acc[5][2][2];                                 // [set][frag][row-half]
#pragma unroll
    for (int s = 0; s < 5; ++s)
#pragma unroll
        for (int f = 0; f < 2; ++f)
#pragma unroll
            for (int mi = 0; mi < 2; ++mi) acc[s][f][mi] = (f32x4)(0.0f);

    s16x8 A[4][2];

#define N_STAGE(KB, BUF) do {                                                    \
    _Pragma("unroll")                                                            \
    for (int fl = w; fl < 12; fl += 4) {                                         \
        int rfl_ = (fl < 10) ? fl : fl - 10;            /* slots 10,11: dup */   \
        int s_ = rfl_ >> 1, f_ = rfl_ & 1;                                       \
        const short* src_ = Wpk +                                                \
            ((size_t)(((KB) * 5 + s_) * 20 + y * 2 + f_) * 64 + l) * 8;          \
        dma16(src_, &Bs[BUF][fl * 512]);                                         \
    } } while (0)

#define N_ALOAD(KB, SLOT) do {                                                   \
    const short* Hb_ = ((KB) >= 10) ? HR : HL;                                   \
    const int kb32_ = (KB) - (((KB) >= 10) ? 10 : 0);                            \
    const short* p_ = Hb_ +                                                      \
        (size_t)((kb32_ * 4 + quad) * BATCH + w * 32 + lane16) * 8;              \
    A[SLOT][0] = *(const s16x8*)(p_);                                            \
    A[SLOT][1] = *(const s16x8*)(p_ + 16 * 8);                                   \
} while (0)

    N_STAGE(0, 0); N_ALOAD(0, 0);
    N_STAGE(1, 1); N_ALOAD(1, 1);
    N_STAGE(2, 2); N_ALOAD(2, 2);

#define N_STEP(ST, WAITN) do {                                                   \
    asm volatile("s_waitcnt vmcnt(" #WAITN ")" ::: "memory");                    \
    __builtin_amdgcn_s_barrier();                                                \
    asm volatile("" ::: "memory");                                               \
    if ((ST) + 3 < 20) { N_STAGE((ST) + 3, ((ST) + 3) & 3);                      \
                         N_ALOAD((ST) + 3, ((ST) + 3) & 3); }                    \
    _Pragma("unroll")                                                            \
    for (int s_ = 0; s_ < 5; ++s_) {                                             \
        _Pragma("unroll")                                                        \
        for (int f_ = 0; f_ < 2; ++f_) {                                         \
            s16x8 b_ = *(const s16x8*)&Bs[(ST) & 3][(s_ * 2 + f_) * 512 + l * 8];\
            acc[s_][f_][0] = mfma16(A[(ST) & 3][0], b_, acc[s_][f_][0]);         \
            acc[s_][f_][1] = mfma16(A[(ST) & 3][1], b_, acc[s_][f_][1]);         \
        }                                                                        \
    } } while (0)

    N_STEP(0, 10);  N_STEP(1, 10);  N_STEP(2, 10);  N_STEP(3, 10);  N_STEP(4, 10);
    N_STEP(5, 10);  N_STEP(6, 10);  N_STEP(7, 10);  N_STEP(8, 10);  N_STEP(9, 10);
    N_STEP(10, 10); N_STEP(11, 10); N_STEP(12, 10); N_STEP(13, 10); N_STEP(14, 10);
    N_STEP(15, 10); N_STEP(16, 10); N_STEP(17, 10); N_STEP(18, 5);  N_STEP(19, 0);

#undef N_STEP
#undef N_ALOAD
#undef N_STAGE

#pragma unroll
    for (int f = 0; f < 2; ++f) {
        const int col = y * 32 + f * 16 + lane16;
        const bool valid = col < MEM;
        float bff = 0, bi = 0, bo = 0, bu = 0;
        if (valid) {
            bff = b_fioux[col]; bi = b_fioux[300 + col];
            bo = b_fioux[600 + col]; bu = b_fioux[900 + col];
        }
#pragma unroll
        for (int mi = 0; mi < 2; ++mi)
#pragma unroll
            for (int r = 0; r < 4; ++r) {
                int row = w * 32 + mi * 16 + quad * 4 + r;
                size_t hIdx = (size_t)node * HNODE +
                              (size_t)((col >> 3) * BATCH + row) * 8 + (col & 7);
                if (valid) {
                    float cl = (float)C[((size_t)li * BATCH + row) * MEM + col];
                    float cr = (float)C[((size_t)ri * BATCH + row) * MEM + col];
                    float ig = sigf(acc[0][f][mi][r] + bi);
                    float og = sigf(acc[1][f][mi][r] + bo);
                    float ug = tanhf_(acc[2][f][mi][r] + bu);
                    float fl = sigf(acc[3][f][mi][r] + bff);
                    float fr = sigf(acc[4][f][mi][r] + bff);
                    float c = ig * ug + fl * cl + fr * cr;
                    float h = og * tanhf_(c);
                    C[((size_t)node * BATCH + row) * MEM + col] = (half_t)c;
                    H[hIdx] = f2bf(h);
                    if (out) {
                        out[row * MEM + col] = c;
                        out[OUT_HALF + row * MEM + col] = h;
                    }
                } else {
                    H[hIdx] = 0;
                }
            }
    }
}

extern "C" void kernel_launch(void* const* d_in, const int* in_sizes, int n_in,
                              void* d_out, int out_size, void* d_ws, size_t ws_size,
                              hipStream_t stream) {
    const float* inputs  = (const float*)d_in[0];
    const float* Wfioux  = (const float*)d_in[1];
    const float* b_fioux = (const float*)d_in[2];
    const float* Wiouh   = (const float*)d_in[3];
    const float* Wfh     = (const float*)d_in[4];
    const int*   left_idx  = (const int*)d_in[5];
    const int*   right_idx = (const int*)d_in[6];

    half_t* C   = (half_t*)d_ws;                              // [1023][128][300] fp16
    short*  H   = (short*)(C + (size_t)NODES * BATCH * MEM);  // [1023] fragment-ready nodes
    short* WpkN = H + (size_t)NODES * HNODE;                  // 2000 frag-blocks
    short* WpkL = WpkN + (size_t)2000 * 512;                  // 600 frag-blocks
    short* X    = WpkL + (size_t)600 * 512;                   // [512] fragment-ready leaves
    float* out  = (float*)d_out;

    pack_x2<<<(LEAVES * BATCH * KB_CNT + 255) / 256, 256, 0, stream>>>(inputs, X);
    pack_leaf_w<<<150, 256, 0, stream>>>(Wfioux, WpkL);
    pack_node_w<<<500, 256, 0, stream>>>(Wiouh, Wfh, WpkN);

    leaf_mfma<<<LEAVES * 5, 256, 0, stream>>>(X, WpkL, b_fioux, C, H);

    static const int starts[9] = {512, 768, 896, 960, 992, 1008, 1016, 1020, 1022};
    static const int sizes [9] = {256, 128,  64,  32,  16,    8,    4,    2,    1};
    for (int lvl = 0; lvl < 9; ++lvl) {
        bool root = (lvl == 8);
        node_mfma<<<sizes[lvl] * 10, 256, 0, stream>>>(
            WpkN, b_fioux, left_idx, right_idx, C, H, starts[lvl], sizes[lvl],
            root ? out : nullptr);
    }
}

// Round 10
// 627.995 us; speedup vs baseline: 1.0316x; 1.0065x over previous
//
#include <hip/hip_runtime.h>
#include <cstdint>

#define BATCH 128
#define NODES 1023
#define LEAVES 512
#define IN_DIM 300
#define MEM 300
#define NP 320              // padded per-set N (and per-child K)
#define OUT_HALF (BATCH*MEM)

typedef __bf16   bf16x8 __attribute__((ext_vector_type(8)));
typedef short    s16x8  __attribute__((ext_vector_type(8)));
typedef short    s16x4  __attribute__((ext_vector_type(4)));
typedef float    f32x4  __attribute__((ext_vector_type(4)));
typedef _Float16 half_t;

__device__ __forceinline__ short f2bf(float f) {
    unsigned u = __float_as_uint(f);
    u += 0x7fff + ((u >> 16) & 1);
    return (short)(u >> 16);
}
__device__ __forceinline__ float sigf(float x)  { return 1.0f / (1.0f + __expf(-x)); }
__device__ __forceinline__ float tanhf_(float x){ return 1.0f - 2.0f / (1.0f + __expf(2.0f * x)); }

__device__ __forceinline__ f32x4 mfma16(s16x8 a, s16x8 b, f32x4 c) {
    return __builtin_amdgcn_mfma_f32_16x16x32_bf16(
        __builtin_bit_cast(bf16x8, a), __builtin_bit_cast(bf16x8, b), c, 0, 0, 0);
}

// async 16B/lane global->LDS: lds dst = wave-uniform base + lane*16
__device__ __forceinline__ void dma16(const short* src, short* ldsBase) {
    __builtin_amdgcn_global_load_lds(
        (const __attribute__((address_space(1))) unsigned int*)src,
        (__attribute__((address_space(3))) unsigned int*)ldsBase,
        16, 0, 0);
}

// ---------- weight packing: B-fragment order ----------
// frag-block (kb,s,nb): 64 lanes x 8 bf16; lane l holds B[k=kb*32+(l>>4)*8+j][n=nb*16+(l&15)]
__global__ __launch_bounds__(256) void pack_node_w(
    const float* __restrict__ Wiouh, const float* __restrict__ Wfh, short* __restrict__ Wpk)
{
    int gid = blockIdx.x * 256 + threadIdx.x;           // 2000 frags * 64 lanes
    if (gid >= 2000 * 64) return;
    int fb = gid >> 6, l = gid & 63;
    int kb = fb / 100, rem = fb % 100, s = rem / 20, nb = rem % 20;
    int n = nb * 16 + (l & 15);
    int kbase = kb * 32 + (l >> 4) * 8;                 // k' in [0,640)
    short v[8];
#pragma unroll
    for (int j = 0; j < 8; ++j) {
        int kp = kbase + j;
        int side = kp >= NP;
        int kk = kp - side * NP;
        float f = 0.0f;
        if (kk < MEM && n < MEM) {
            int k = side * MEM + kk;
            f = (s < 3) ? Wiouh[(size_t)k * 900 + s * 300 + n]
                        : Wfh[(size_t)k * 600 + (s - 3) * 300 + n];
        }
        v[j] = f2bf(f);
    }
    *(s16x8*)&Wpk[(size_t)gid * 8] = *(s16x8*)v;
}

__global__ __launch_bounds__(256) void pack_leaf_w(
    const float* __restrict__ Wfioux, short* __restrict__ Wpk)
{
    int gid = blockIdx.x * 256 + threadIdx.x;           // 600 frags * 64 lanes
    if (gid >= 600 * 64) return;
    int fb = gid >> 6, l = gid & 63;
    int kb = fb / 60, rem = fb % 60, s = rem / 20, nb = rem % 20;
    int n = nb * 16 + (l & 15);
    int kbase = kb * 32 + (l >> 4) * 8;                 // k' in [0,320)
    short v[8];
#pragma unroll
    for (int j = 0; j < 8; ++j) {
        int kp = kbase + j;
        float f = 0.0f;
        if (kp < IN_DIM && n < MEM)
            f = Wfioux[(size_t)kp * 1200 + (s + 1) * 300 + n];
        v[j] = f2bf(f);
    }
    *(s16x8*)&Wpk[(size_t)gid * 8] = *(s16x8*)v;
}

// ---------- leaf-input packing: X[leaf][b][kp] bf16, kp padded to 320 ----------
__global__ __launch_bounds__(256) void pack_x(
    const float* __restrict__ inputs, short* __restrict__ X)
{
    int gid = blockIdx.x * 256 + threadIdx.x;           // 512*128*80 quads
    if (gid >= LEAVES * BATCH * (NP / 4)) return;
    int q = gid % (NP / 4);
    int rb = gid / (NP / 4);
    int b = rb % BATCH, leaf = rb / BATCH;
    short v[4] = {0, 0, 0, 0};
    if (q < IN_DIM / 4) {
        f32x4 f = *(const f32x4*)&inputs[((size_t)b * NODES + leaf) * IN_DIM + q * 4];
        v[0] = f2bf(f[0]); v[1] = f2bf(f[1]); v[2] = f2bf(f[2]); v[3] = f2bf(f[3]);
    }
    *(s16x4*)&X[(size_t)gid * 4] = *(s16x4*)v;
}

// ---------- leaf GEMM+gates: block = 1 leaf x 64-col group ----------
// (round-3 version, verbatim: 4xM wave split, 4-buf ring depth-3, counted
// vmcnt(10) steady; XCD swizzle groups a leaf's 5 col-groups on one XCD.)
__global__ __launch_bounds__(256, 3) void leaf_mfma(
    const short* __restrict__ X, const short* __restrict__ Wpk,
    const float* __restrict__ b_fioux, half_t* __restrict__ C, short* __restrict__ H)
{
    __shared__ short Bs[4][12 * 512];                   // 4 ring bufs x 12 frags x 1KB
    const int t = threadIdx.x;
    const int l = t & 63, w = t >> 6;                   // 4 waves, w = row-group
    const int lane16 = l & 15, quad = l >> 4;

    // bid = (leaf%8) + 8*(y + 5*(leaf/8))  ->  decode:
    const int bid = blockIdx.x;
    const int xcd = bid & 7, tt = bid >> 3;
    const int y = tt % 5;                               // 64-col group 0..4
    const int leaf = (tt / 5) * 8 + xcd;

    const short* Xb = X + (size_t)leaf * BATCH * NP;

    f32x4 acc[3][4][2];                                 // [set][frag][row-half]
#pragma unroll
    for (int s = 0; s < 3; ++s)
#pragma unroll
        for (int f = 0; f < 4; ++f)
#pragma unroll
            for (int mi = 0; mi < 2; ++mi) acc[s][f][mi] = (f32x4)(0.0f);

    s16x8 A[4][2];                                      // A-fragment ring (static idx only)

#define L_STAGE(KB, BUF) do {                                                    \
    _Pragma("unroll")                                                            \
    for (int fl = w; fl < 12; fl += 4) {                                         \
        int s_ = fl >> 2, f_ = fl & 3;                                           \
        const short* src_ = Wpk +                                                \
            ((size_t)(((KB) * 3 + s_) * 20 + y * 4 + f_) * 64 + l) * 8;          \
        dma16(src_, &Bs[BUF][fl * 512]);                                         \
    } } while (0)

#define L_ALOAD(KB, SLOT) do {                                                   \
    const int koff_ = (KB) * 32 + quad * 8;                                      \
    A[SLOT][0] = *(const s16x8*)(Xb + (size_t)(w * 32 + lane16) * NP + koff_);   \
    A[SLOT][1] = *(const s16x8*)(Xb + (size_t)(w * 32 + 16 + lane16) * NP + koff_); \
} while (0)

    // prologue: issue steps 0,1,2 (15 vmem ops per wave in flight)
    L_STAGE(0, 0); L_ALOAD(0, 0);
    L_STAGE(1, 1); L_ALOAD(1, 1);
    L_STAGE(2, 2); L_ALOAD(2, 2);

// waitcnt BEFORE barrier: guarantees every wave's step-ST stage is complete when
// any wave crosses. issue AFTER barrier: ring distance 3 makes the WAR on buffer
// (ST+3)&3 == (ST-1)&3 safe (its readers finished before this barrier).
#define L_STEP(ST, WAITN) do {                                                   \
    asm volatile("s_waitcnt vmcnt(" #WAITN ")" ::: "memory");                    \
    __builtin_amdgcn_s_barrier();                                                \
    asm volatile("" ::: "memory");                                               \
    if ((ST) + 3 < 10) { L_STAGE((ST) + 3, ((ST) + 3) & 3);                      \
                         L_ALOAD((ST) + 3, ((ST) + 3) & 3); }                    \
    _Pragma("unroll")                                                            \
    for (int s_ = 0; s_ < 3; ++s_) {                                             \
        _Pragma("unroll")                                                        \
        for (int f_ = 0; f_ < 4; ++f_) {                                         \
            s16x8 b_ = *(const s16x8*)&Bs[(ST) & 3][(s_ * 4 + f_) * 512 + l * 8];\
            acc[s_][f_][0] = mfma16(A[(ST) & 3][0], b_, acc[s_][f_][0]);         \
            acc[s_][f_][1] = mfma16(A[(ST) & 3][1], b_, acc[s_][f_][1]);         \
        }                                                                        \
    } } while (0)

    L_STEP(0, 10); L_STEP(1, 10); L_STEP(2, 10); L_STEP(3, 10); L_STEP(4, 10);
    L_STEP(5, 10); L_STEP(6, 10); L_STEP(7, 10); L_STEP(8, 5);  L_STEP(9, 0);

#undef L_STEP
#undef L_ALOAD
#undef L_STAGE

#pragma unroll
    for (int f = 0; f < 4; ++f) {
        const int col = y * 64 + f * 16 + lane16;
        const bool valid = col < MEM;
        float bi = 0, bo = 0, bu = 0;
        if (valid) { bi = b_fioux[300 + col]; bo = b_fioux[600 + col]; bu = b_fioux[900 + col]; }
#pragma unroll
        for (int mi = 0; mi < 2; ++mi)
#pragma unroll
            for (int r = 0; r < 4; ++r) {
                int b = w * 32 + mi * 16 + quad * 4 + r;
                size_t hIdx = ((size_t)leaf * BATCH + b) * NP + col;
                if (valid) {
                    float ig = sigf(acc[0][f][mi][r] + bi);
                    float og = sigf(acc[1][f][mi][r] + bo);
                    float ug = tanhf_(acc[2][f][mi][r] + bu);
                    float c = ig * ug;
                    float h = og * tanhf_(c);
                    C[((size_t)leaf * BATCH + b) * MEM + col] = (half_t)c;
                    H[hIdx] = f2bf(h);
                } else {
                    H[hIdx] = 0;
                }
            }
    }
}

// ---------- internal node GEMM+gates (levels 0-2): round-3 config verbatim ----------
// K32, 20 steps, 12-frag staging (slots 10,11 dup), 4-buf ring depth-3,
// steady vmcnt(10), 3 blocks/CU. XCD swizzle groups a node's 10 col-groups.
__global__ __launch_bounds__(256, 3) void node_mfma(
    const short* __restrict__ Wpk, const float* __restrict__ b_fioux,
    const int* __restrict__ left_idx, const int* __restrict__ right_idx,
    half_t* __restrict__ C, short* __restrict__ H,
    int level_start, int level_size, float* __restrict__ out)
{
    __shared__ short Bs[4][12 * 512];                   // 4 ring bufs x 12KB
    const int t = threadIdx.x;
    const int l = t & 63, w = t >> 6;                   // 4 waves, w = row-group
    const int lane16 = l & 15, quad = l >> 4;

    const int bid = blockIdx.x;
    int nidx, y;
    if ((level_size & 7) == 0) {
        const int xcd = bid & 7, tt = bid >> 3;
        y = tt % 10;
        nidx = (tt / 10) * 8 + xcd;
    } else {
        nidx = bid % level_size;
        y = bid / level_size;
    }
    const int node = level_start + nidx;

    const int li = left_idx[node], ri = right_idx[node];
    const short* HL = H + (size_t)li * BATCH * NP;
    const short* HR = H + (size_t)ri * BATCH * NP;

    f32x4 acc[5][2][2];                                 // [set][frag][row-half]
#pragma unroll
    for (int s = 0; s < 5; ++s)
#pragma unroll
        for (int f = 0; f < 2; ++f)
#pragma unroll
            for (int mi = 0; mi < 2; ++mi) acc[s][f][mi] = (f32x4)(0.0f);

    s16x8 A[4][2];

#define N_STAGE(KB, BUF) do {                                                    \
    _Pragma("unroll")                                                            \
    for (int fl = w; fl < 12; fl += 4) {                                         \
        int rfl_ = (fl < 10) ? fl : fl - 10;            /* slots 10,11: dup */   \
        int s_ = rfl_ >> 1, f_ = rfl_ & 1;                                       \
        const short* src_ = Wpk +                                                \
            ((size_t)(((KB) * 5 + s_) * 20 + y * 2 + f_) * 64 + l) * 8;          \
        dma16(src_, &Bs[BUF][fl * 512]);                                         \
    } } while (0)

#define N_ALOAD(KB, SLOT) do {                                                   \
    const short* Hb_ = (((KB) >= 10) ? HR : HL) +                                \
                       ((KB) - (((KB) >= 10) ? 10 : 0)) * 32 + quad * 8;         \
    A[SLOT][0] = *(const s16x8*)(Hb_ + (size_t)(w * 32 + lane16) * NP);          \
    A[SLOT][1] = *(const s16x8*)(Hb_ + (size_t)(w * 32 + 16 + lane16) * NP);     \
} while (0)

    N_STAGE(0, 0); N_ALOAD(0, 0);
    N_STAGE(1, 1); N_ALOAD(1, 1);
    N_STAGE(2, 2); N_ALOAD(2, 2);

#define N_STEP(ST, WAITN) do {                                                   \
    asm volatile("s_waitcnt vmcnt(" #WAITN ")" ::: "memory");                    \
    __builtin_amdgcn_s_barrier();                                                \
    asm volatile("" ::: "memory");                                               \
    if ((ST) + 3 < 20) { N_STAGE((ST) + 3, ((ST) + 3) & 3);                      \
                         N_ALOAD((ST) + 3, ((ST) + 3) & 3); }                    \
    _Pragma("unroll")                                                            \
    for (int s_ = 0; s_ < 5; ++s_) {                                             \
        _Pragma("unroll")                                                        \
        for (int f_ = 0; f_ < 2; ++f_) {                                         \
            s16x8 b_ = *(const s16x8*)&Bs[(ST) & 3][(s_ * 2 + f_) * 512 + l * 8];\
            acc[s_][f_][0] = mfma16(A[(ST) & 3][0], b_, acc[s_][f_][0]);         \
            acc[s_][f_][1] = mfma16(A[(ST) & 3][1], b_, acc[s_][f_][1]);         \
        }                                                                        \
    } } while (0)

    N_STEP(0, 10);  N_STEP(1, 10);  N_STEP(2, 10);  N_STEP(3, 10);  N_STEP(4, 10);
    N_STEP(5, 10);  N_STEP(6, 10);  N_STEP(7, 10);  N_STEP(8, 10);  N_STEP(9, 10);
    N_STEP(10, 10); N_STEP(11, 10); N_STEP(12, 10); N_STEP(13, 10); N_STEP(14, 10);
    N_STEP(15, 10); N_STEP(16, 10); N_STEP(17, 10); N_STEP(18, 5);  N_STEP(19, 0);

#undef N_STEP
#undef N_ALOAD
#undef N_STAGE

#pragma unroll
    for (int f = 0; f < 2; ++f) {
        const int col = y * 32 + f * 16 + lane16;
        const bool valid = col < MEM;
        float bff = 0, bi = 0, bo = 0, bu = 0;
        if (valid) {
            bff = b_fioux[col]; bi = b_fioux[300 + col];
            bo = b_fioux[600 + col]; bu = b_fioux[900 + col];
        }
#pragma unroll
        for (int mi = 0; mi < 2; ++mi)
#pragma unroll
            for (int r = 0; r < 4; ++r) {
                int row = w * 32 + mi * 16 + quad * 4 + r;
                size_t hIdx = ((size_t)node * BATCH + row) * NP + col;
                if (valid) {
                    float cl = (float)C[((size_t)li * BATCH + row) * MEM + col];
                    float cr = (float)C[((size_t)ri * BATCH + row) * MEM + col];
                    float ig = sigf(acc[0][f][mi][r] + bi);
                    float og = sigf(acc[1][f][mi][r] + bo);
                    float ug = tanhf_(acc[2][f][mi][r] + bu);
                    float fl = sigf(acc[3][f][mi][r] + bff);
                    float fr = sigf(acc[4][f][mi][r] + bff);
                    float c = ig * ug + fl * cl + fr * cr;
                    float h = og * tanhf_(c);
                    C[((size_t)node * BATCH + row) * MEM + col] = (half_t)c;
                    H[hIdx] = f2bf(h);
                    if (out) {
                        out[row * MEM + col] = c;
                        out[OUT_HALF + row * MEM + col] = h;
                    }
                } else {
                    H[hIdx] = 0;
                }
            }
    }
}

// ---------- internal node GEMM+gates, K64 (tail levels 3-8): round-5 verbatim ----------
// 10 steps over K'=640 -> half the serial barrier chain. Tail levels are
// latency-bound (all blocks co-resident at 2 blk/CU: <= 320 blocks <= 512),
// so per-level duration = per-block critical path = step count x step latency.
__global__ __launch_bounds__(256, 2) void node_k64(
    const short* __restrict__ Wpk, const float* __restrict__ b_fioux,
    const int* __restrict__ left_idx, const int* __restrict__ right_idx,
    half_t* __restrict__ C, short* __restrict__ H,
    int level_start, int level_size, float* __restrict__ out)
{
    __shared__ short Bs[4][20 * 512];                   // 4 ring bufs x 20KB = 80KB
    const int t = threadIdx.x;
    const int l = t & 63, w = t >> 6;                   // 4 waves, w = row-group
    const int lane16 = l & 15, quad = l >> 4;

    const int bid = blockIdx.x;
    int nidx, y;
    if ((level_size & 7) == 0) {
        const int xcd = bid & 7, tt = bid >> 3;
        y = tt % 10;
        nidx = (tt / 10) * 8 + xcd;
    } else {
        nidx = bid % level_size;
        y = bid / level_size;
    }
    const int node = level_start + nidx;

    const int li = left_idx[node], ri = right_idx[node];
    const short* HL = H + (size_t)li * BATCH * NP;
    const short* HR = H + (size_t)ri * BATCH * NP;

    f32x4 acc[5][2][2];                                 // [set][frag][row-half]
#pragma unroll
    for (int s = 0; s < 5; ++s)
#pragma unroll
        for (int f = 0; f < 2; ++f)
#pragma unroll
            for (int mi = 0; mi < 2; ++mi) acc[s][f][mi] = (f32x4)(0.0f);

    s16x8 A[4][2][2];                                   // ring: 4 slots x ksub x row-half

// frag layout in LDS buffer: fl = ksub*10 + s*2 + f  (ksub = which 32-K half)
#define K_STAGE(ST, BUF) do {                                                    \
    _Pragma("unroll")                                                            \
    for (int fl = w; fl < 20; fl += 4) {               /* 5 frags per wave */    \
        int ksub_ = fl / 10, rem_ = fl - ksub_ * 10;                             \
        int s_ = rem_ >> 1, f_ = rem_ & 1;                                       \
        int kb32_ = (ST) * 2 + ksub_;                                            \
        const short* src_ = Wpk +                                                \
            ((size_t)((kb32_ * 5 + s_) * 20 + y * 2 + f_) * 64 + l) * 8;         \
        dma16(src_, &Bs[BUF][fl * 512]);                                         \
    } } while (0)

#define K_ALOAD(ST, SLOT) do {                                                   \
    const int side_ = (ST) >= 5;                                                 \
    const short* Hb_ = (side_ ? HR : HL) + ((ST) - side_ * 5) * 64 + quad * 8;   \
    _Pragma("unroll")                                                            \
    for (int ksub_ = 0; ksub_ < 2; ++ksub_) {                                    \
        A[SLOT][ksub_][0] = *(const s16x8*)(Hb_ +                                \
            (size_t)(w * 32 + lane16) * NP + ksub_ * 32);                        \
        A[SLOT][ksub_][1] = *(const s16x8*)(Hb_ +                                \
            (size_t)(w * 32 + 16 + lane16) * NP + ksub_ * 32);                   \
    } } while (0)

    K_STAGE(0, 0); K_ALOAD(0, 0);
    K_STAGE(1, 1); K_ALOAD(1, 1);
    K_STAGE(2, 2); K_ALOAD(2, 2);

#define K_STEP(ST, WAITN) do {                                                   \
    asm volatile("s_waitcnt vmcnt(" #WAITN ")" ::: "memory");                    \
    __builtin_amdgcn_s_barrier();                                                \
    asm volatile("" ::: "memory");                                               \
    if ((ST) + 3 < 10) { K_STAGE((ST) + 3, ((ST) + 3) & 3);                      \
                         K_ALOAD((ST) + 3, ((ST) + 3) & 3); }                    \
    _Pragma("unroll")                                                            \
    for (int ks_ = 0; ks_ < 2; ++ks_) {                                          \
        _Pragma("unroll")                                                        \
        for (int s_ = 0; s_ < 5; ++s_) {                                         \
            _Pragma("unroll")                                                    \
            for (int f_ = 0; f_ < 2; ++f_) {                                     \
                s16x8 b_ = *(const s16x8*)                                       \
                    &Bs[(ST) & 3][(ks_ * 10 + s_ * 2 + f_) * 512 + l * 8];       \
                acc[s_][f_][0] = mfma16(A[(ST) & 3][ks_][0], b_, acc[s_][f_][0]);\
                acc[s_][f_][1] = mfma16(A[(ST) & 3][ks_][1], b_, acc[s_][f_][1]);\
            }                                                                    \
        }                                                                        \
    } } while (0)

    K_STEP(0, 18); K_STEP(1, 18); K_STEP(2, 18); K_STEP(3, 18); K_STEP(4, 18);
    K_STEP(5, 18); K_STEP(6, 18); K_STEP(7, 18); K_STEP(8, 9);  K_STEP(9, 0);

#undef K_STEP
#undef K_ALOAD
#undef K_STAGE

#pragma unroll
    for (int f = 0; f < 2; ++f) {
        const int col = y * 32 + f * 16 + lane16;
        const bool valid = col < MEM;
        float bff = 0, bi = 0, bo = 0, bu = 0;
        if (valid) {
            bff = b_fioux[col]; bi = b_fioux[300 + col];
            bo = b_fioux[600 + col]; bu = b_fioux[900 + col];
        }
#pragma unroll
        for (int mi = 0; mi < 2; ++mi)
#pragma unroll
            for (int r = 0; r < 4; ++r) {
                int row = w * 32 + mi * 16 + quad * 4 + r;
                size_t hIdx = ((size_t)node * BATCH + row) * NP + col;
                if (valid) {
                    float cl = (float)C[((size_t)li * BATCH + row) * MEM + col];
                    float cr = (float)C[((size_t)ri * BATCH + row) * MEM + col];
                    float ig = sigf(acc[0][f][mi][r] + bi);
                    float og = sigf(acc[1][f][mi][r] + bo);
                    float ug = tanhf_(acc[2][f][mi][r] + bu);
                    float fl = sigf(acc[3][f][mi][r] + bff);
                    float fr = sigf(acc[4][f][mi][r] + bff);
                    float c = ig * ug + fl * cl + fr * cr;
                    float h = og * tanhf_(c);
                    C[((size_t)node * BATCH + row) * MEM + col] = (half_t)c;
                    H[hIdx] = f2bf(h);
                    if (out) {
                        out[row * MEM + col] = c;
                        out[OUT_HALF + row * MEM + col] = h;
                    }
                } else {
                    H[hIdx] = 0;
                }
            }
    }
}

extern "C" void kernel_launch(void* const* d_in, const int* in_sizes, int n_in,
                              void* d_out, int out_size, void* d_ws, size_t ws_size,
                              hipStream_t stream) {
    const float* inputs  = (const float*)d_in[0];
    const float* Wfioux  = (const float*)d_in[1];
    const float* b_fioux = (const float*)d_in[2];
    const float* Wiouh   = (const float*)d_in[3];
    const float* Wfh     = (const float*)d_in[4];
    const int*   left_idx  = (const int*)d_in[5];
    const int*   right_idx = (const int*)d_in[6];

    half_t* C   = (half_t*)d_ws;                              // [1023][128][300] fp16
    short*  H   = (short*)(C + (size_t)NODES * BATCH * MEM);  // [1023][128][320] bf16
    short* WpkN = H + (size_t)NODES * BATCH * NP;             // 2000 frag-blocks
    short* WpkL = WpkN + (size_t)2000 * 512;                  // 600 frag-blocks
    short* X    = WpkL + (size_t)600 * 512;                   // [512][128][320] bf16
    float* out  = (float*)d_out;

    pack_x<<<(LEAVES * BATCH * (NP / 4) + 255) / 256, 256, 0, stream>>>(inputs, X);
    pack_leaf_w<<<150, 256, 0, stream>>>(Wfioux, WpkL);
    pack_node_w<<<500, 256, 0, stream>>>(Wiouh, Wfh, WpkN);

    leaf_mfma<<<LEAVES * 5, 256, 0, stream>>>(X, WpkL, b_fioux, C, H);

    static const int starts[9] = {512, 768, 896, 960, 992, 1008, 1016, 1020, 1022};
    static const int sizes [9] = {256, 128,  64,  32,  16,    8,    4,    2,    1};
    for (int lvl = 0; lvl < 9; ++lvl) {
        bool root = (lvl == 8);
        if (lvl < 3) {
            node_mfma<<<sizes[lvl] * 10, 256, 0, stream>>>(
                WpkN, b_fioux, left_idx, right_idx, C, H, starts[lvl], sizes[lvl],
                nullptr);
        } else {
            node_k64<<<sizes[lvl] * 10, 256, 0, stream>>>(
                WpkN, b_fioux, left_idx, right_idx, C, H, starts[lvl], sizes[lvl],
                root ? out : nullptr);
        }
    }
}